// Round 5
// baseline (229.424 us; speedup 1.0000x reference)
//
#include <hip/hip_runtime.h>
#include <hip/hip_bf16.h>

// B=4, S=4096, E=256, NC=16, fp32 in/out. 3 launches:
//  qkv_gemm: fp32-read + VALU-pack staging, MFMA, LDS-routed dense epilogues
//            (Q plain*1/16, K block-swizzled rows, V chunk-tiled slabs)
//  flash:    Q-tile 256/block (u=4 subtiles/wave), 1 block/CU, K sbuf + V dbuf
//            (64 KB LDS), 2 barriers/chunk pipelined, no-max softmax,
//            additive key-split partials (NS=4), swizzled Opart rows
//  proj:     MFMA output projection + slice-sum + normalize (dbuf staging)

#define S_ 4096
#define E_ 256
#define B_ 4
#define NC_ 16
#define BS_ (B_ * S_)
#define NS_ 4

typedef __attribute__((ext_vector_type(8))) short bf16x8;
typedef __attribute__((ext_vector_type(4))) float f32x4;

__device__ __forceinline__ unsigned short bf16_rtne(float f) {
    unsigned int u = __float_as_uint(f);
    return (unsigned short)((u + 0x7FFFu + ((u >> 16) & 1u)) >> 16);
}
__device__ __forceinline__ bf16x8 pack8(f32x4 a, f32x4 b) {
    bf16x8 r;
#pragma unroll
    for (int i = 0; i < 4; i++) r[i] = (short)bf16_rtne(a[i]);
#pragma unroll
    for (int i = 0; i < 4; i++) r[4 + i] = (short)bf16_rtne(b[i]);
    return r;
}
__device__ __forceinline__ void gl_lds16(const void* g, void* lds) {
    __builtin_amdgcn_global_load_lds(
        (const __attribute__((address_space(1))) unsigned int*)g,
        (__attribute__((address_space(3))) unsigned int*)lds, 16, 0, 0);
}

// ---------------------------------------------------------------------------
// qkv_gemm. Grid (3 sel, BS_/64). 256 thr = 4 waves; wave: 16 rows x 256 cols.
// fp32 coalesced loads + pack8 + ds_write_b128 into fragment-slot layout.
// ---------------------------------------------------------------------------
__global__ __launch_bounds__(256) void qkv_gemm(
    const float* __restrict__ x, const float* __restrict__ wq,
    const float* __restrict__ wk, const float* __restrict__ wv,
    const float* __restrict__ bq, const float* __restrict__ bk,
    const float* __restrict__ bv, short* __restrict__ Qb,
    short* __restrict__ Kb, short* __restrict__ Vtc) {
    __shared__ bf16x8 xt[256];   // [row(64)][quad(4)] packets, 4 KB
    __shared__ bf16x8 wt[1024];  // [n(256)][quad(4)] packets, 16 KB
    __shared__ short epi[16896]; // 64x264 (Q/K) or 2x8192 slabs (V), 33 KB

    int t = threadIdx.x;
    int sel = blockIdx.x, m0 = blockIdx.y * 64;
    int lane = t & 63, wid = t >> 6, quad = lane >> 4, idx = lane & 15;

    const float* w = (sel == 0) ? wq : (sel == 1) ? wk : wv;
    const float* bias = (sel == 0) ? bq : (sel == 1) ? bk : bv;

    const float* xsrc = x + (size_t)(m0 + (t >> 2)) * E_ + (t & 3) * 8;

    f32x4 zf = {0.f, 0.f, 0.f, 0.f};
    f32x4 acc[16];
#pragma unroll
    for (int i = 0; i < 16; i++) acc[i] = zf;

    for (int kc = 0; kc < E_; kc += 32) {
        f32x4 a0 = *(const f32x4*)(xsrc + kc);
        f32x4 a1 = *(const f32x4*)(xsrc + kc + 4);
        xt[t] = pack8(a0, a1);
#pragma unroll
        for (int i = 0; i < 4; i++) {
            int p = i * 256 + t;
            const float* ws = w + (size_t)(p >> 2) * E_ + (p & 3) * 8 + kc;
            f32x4 b0 = *(const f32x4*)ws;
            f32x4 b1 = *(const f32x4*)(ws + 4);
            wt[p] = pack8(b0, b1);
        }
        __syncthreads();
        bf16x8 af = xt[(wid * 16 + idx) * 4 + quad];
#pragma unroll
        for (int ct = 0; ct < 16; ct++)
            acc[ct] = __builtin_amdgcn_mfma_f32_16x16x32_bf16(
                af, wt[(ct * 16 + idx) * 4 + quad], acc[ct], 0, 0, 0);
        __syncthreads();
    }

    // ---- epilogue via LDS for dense global writes ----
    int qr = quad * 4; // rows qr..qr+3 within wave's 16-row band
    if (sel == 2) {
        // V: write into chunk-slab layout with 16B-block swizzle
#pragma unroll
        for (int ct = 0; ct < 16; ct++) {
            int e = ct * 16 + idx;
            float bb = bias[e];
#pragma unroll
            for (int r = 0; r < 4; r++) {
                int mr = wid * 16 + qr + r; // 0..63
                int ckg = mr >> 5, sin = mr & 31;
                int pos = (sin >> 3) ^ ((e >> 1) & 3);
                epi[ckg * 8192 + e * 32 + pos * 8 + (sin & 7)] =
                    (short)bf16_rtne(acc[ct][r] + bb);
            }
        }
        __syncthreads();
        size_t base = ((size_t)((m0 >> 12) * 128 + ((m0 & (S_ - 1)) >> 5))) * 8192;
#pragma unroll
        for (int j = 0; j < 8; j++) {
            int unit = j * 256 + t; // 2048 units of 8 shorts
            *(bf16x8*)(Vtc + base + (size_t)unit * 8) = *(const bf16x8*)&epi[unit * 8];
        }
    } else {
        float alpha = (sel == 0) ? 0.0625f : 1.0f;
#pragma unroll
        for (int ct = 0; ct < 16; ct++) {
            int n = ct * 16 + idx;
            float bb = bias[n];
#pragma unroll
            for (int r = 0; r < 4; r++) {
                int row = wid * 16 + qr + r;
                int col = (sel == 1) ? ((((n >> 3) ^ (row & 7)) << 3) | (n & 7)) : n;
                epi[row * 264 + col] = (short)bf16_rtne((acc[ct][r] + bb) * alpha);
            }
        }
        __syncthreads();
        short* out = (sel == 0) ? Qb : Kb;
#pragma unroll
        for (int j = 0; j < 8; j++) {
            int g = j * 256 + t; // 2048 units: row = g>>5, seg = g&31
            int row = g >> 5, seg = g & 31;
            *(bf16x8*)(out + (size_t)(m0 + row) * E_ + seg * 8) =
                *(const bf16x8*)&epi[row * 264 + seg * 8];
        }
    }
}

// ---------------------------------------------------------------------------
// Flash. Grid (S/256, NS, B). 256 thr = 4 waves; wave owns 64 q-rows as 4
// subtiles (u). LDS 64 KB: K sbuf 16K | V dbuf 2x16K | ps 16K.
// Per 32-key chunk (2 barriers): [bar: K(ck),V(ck) ready] stageV(ck+1);
// QK+exp; [bar] stageK(ck+1); PV.  Unnormalized partial O + rowsum out.
// ---------------------------------------------------------------------------
__global__ __launch_bounds__(256, 1) void flash_attn(
    const short* __restrict__ Qb, const short* __restrict__ Kb,
    const short* __restrict__ Vtc, short* __restrict__ Opart,
    float* __restrict__ lpart) {
    __shared__ __align__(16) short lds[32768]; // 64 KB
    short* kbuf = lds;                          // 8192 shorts
    short* vbuf0 = lds + 8192;
    short* vbuf1 = lds + 16384;
    short* psb = lds + 24576; // [wv*4+u][16][32]

    int t = threadIdx.x;
    int b = blockIdx.z, slice = blockIdx.y, q0 = blockIdx.x * 256;
    int key0 = slice * (S_ / NS_);
    const int nchunk = (S_ / NS_) / 32;
    int lane = t & 63, wv = t >> 6, quad = lane >> 4, idx = lane & 15;

    // Q fragments: 4 subtiles x 8 k-chunks (128 VGPR)
    bf16x8 qf[4][8];
#pragma unroll
    for (int u = 0; u < 4; u++) {
        const short* qrow =
            Qb + (size_t)(b * S_ + q0 + wv * 64 + u * 16 + idx) * E_ + quad * 8;
#pragma unroll
        for (int c = 0; c < 8; c++) qf[u][c] = *(const bf16x8*)(qrow + c * 32);
    }

    f32x4 zf = {0.f, 0.f, 0.f, 0.f};
    f32x4 oacc[4][16];
#pragma unroll
    for (int u = 0; u < 4; u++)
#pragma unroll
        for (int i = 0; i < 16; i++) oacc[u][i] = zf;
    float ls[4][4] = {{0, 0, 0, 0}, {0, 0, 0, 0}, {0, 0, 0, 0}, {0, 0, 0, 0}};

    const short* kg = Kb + (size_t)(b * S_ + key0) * E_ + lane * 8;
    const short* vg = Vtc + ((size_t)(b * 128 + (key0 >> 5))) * 8192 + lane * 8;
    short* psw = psb + (wv * 4) * 512;
    int vsw = (quad ^ ((idx >> 1) & 3)) << 3;

    // prologue: stage K(0) and V(0)
#pragma unroll
    for (int j = 0; j < 4; j++) gl_lds16(kg + (wv * 4 + j) * 512, &kbuf[(wv * 4 + j) * 512]);
#pragma unroll
    for (int j = 0; j < 4; j++) gl_lds16(vg + (wv * 4 + j) * 512, &vbuf0[(wv * 4 + j) * 512]);

    for (int ck = 0; ck < nchunk; ck++) {
        __syncthreads(); // K(ck), V(ck) ready
        if (ck + 1 < nchunk) {
            short* vn = ((ck + 1) & 1) ? vbuf1 : vbuf0;
            const short* vs = vg + (size_t)(ck + 1) * 8192;
#pragma unroll
            for (int j = 0; j < 4; j++)
                gl_lds16(vs + (wv * 4 + j) * 512, &vn[(wv * 4 + j) * 512]);
        }
        // ---- QK^T ----
        f32x4 sc[8];
#pragma unroll
        for (int i = 0; i < 8; i++) sc[i] = zf;
#pragma unroll
        for (int c = 0; c < 8; c++) {
            int p = (((c * 4 + quad) ^ (idx & 7)) << 3);
            bf16x8 k0 = *(const bf16x8*)&kbuf[idx * 256 + p];
            bf16x8 k1 = *(const bf16x8*)&kbuf[(16 + idx) * 256 + p];
#pragma unroll
            for (int u = 0; u < 4; u++) {
                sc[u * 2] = __builtin_amdgcn_mfma_f32_16x16x32_bf16(qf[u][c], k0, sc[u * 2], 0, 0, 0);
                sc[u * 2 + 1] = __builtin_amdgcn_mfma_f32_16x16x32_bf16(qf[u][c], k1, sc[u * 2 + 1], 0, 0, 0);
            }
        }
        // ---- exp + pack P ----
#pragma unroll
        for (int u = 0; u < 4; u++) {
            short* pw = psw + u * 512;
#pragma unroll
            for (int r = 0; r < 4; r++) {
                float p0 = __expf(sc[u * 2][r]);
                float p1 = __expf(sc[u * 2 + 1][r]);
                ls[u][r] += p0 + p1;
                pw[(quad * 4 + r) * 32 + idx] = (short)bf16_rtne(p0);
                pw[(quad * 4 + r) * 32 + 16 + idx] = (short)bf16_rtne(p1);
            }
        }
        __syncthreads(); // all QK reads of kbuf done (also drains V(ck+1))
        if (ck + 1 < nchunk) {
            const short* ks = kg + (size_t)(ck + 1) * 8192;
#pragma unroll
            for (int j = 0; j < 4; j++)
                gl_lds16(ks + (wv * 4 + j) * 512, &kbuf[(wv * 4 + j) * 512]);
        }
        // ---- PV ----
        const short* vc = (ck & 1) ? vbuf1 : vbuf0;
        bf16x8 af[4];
#pragma unroll
        for (int u = 0; u < 4; u++) af[u] = *(const bf16x8*)&psw[u * 512 + idx * 32 + quad * 8];
#pragma unroll
        for (int ct = 0; ct < 16; ct++) {
            bf16x8 v = *(const bf16x8*)&vc[(ct * 16 + idx) * 32 + vsw];
#pragma unroll
            for (int u = 0; u < 4; u++)
                oacc[u][ct] = __builtin_amdgcn_mfma_f32_16x16x32_bf16(af[u], v, oacc[u][ct], 0, 0, 0);
        }
    }
    __syncthreads(); // done with shared compute buffers

    // ---- row sums ----
#pragma unroll
    for (int u = 0; u < 4; u++)
#pragma unroll
        for (int r = 0; r < 4; r++) {
            float v = ls[u][r];
            v += __shfl_xor(v, 1);
            v += __shfl_xor(v, 2);
            v += __shfl_xor(v, 4);
            v += __shfl_xor(v, 8);
            if (idx == 0)
                lpart[(size_t)slice * BS_ + b * S_ + q0 + wv * 64 + u * 16 + quad * 4 + r] = v;
        }

    // ---- Opart epilogue: two 32-row halves via per-wave LDS scratch ----
    short* scr = lds + wv * 8192; // 32 rows x 256 shorts
#pragma unroll
    for (int h = 0; h < 2; h++) {
#pragma unroll
        for (int uu = 0; uu < 2; uu++) {
            int u = h * 2 + uu;
#pragma unroll
            for (int ct = 0; ct < 16; ct++) {
                int e = ct * 16 + idx;
#pragma unroll
                for (int r = 0; r < 4; r++) {
                    int lr = quad * 4 + r;
                    scr[(uu * 16 + lr) * 256 + ((((e >> 3) ^ (lr & 7)) << 3) | (e & 7))] =
                        (short)bf16_rtne(oacc[u][ct][r]);
                }
            }
        }
        size_t obase = ((size_t)slice * BS_ + (size_t)b * S_ + q0 + wv * 64 + h * 32) * E_;
#pragma unroll
        for (int j = 0; j < 16; j++) {
            int unit = j * 64 + lane; // 1024 units of 8 shorts
            *(bf16x8*)(Opart + obase + (size_t)unit * 8) = *(const bf16x8*)&scr[unit * 8];
        }
        __syncthreads(); // reuse scratch safely across halves
    }
}

// ---------------------------------------------------------------------------
// proj: out[m][o] = (sum_ns sum_e Opart[ns][m][e] * wo[o][e]) * (1/16)/ltot + bo
// MFMA 16x16 tiles; A staged dense via global_load_lds (dbuf), wo->bf16 regs.
// ---------------------------------------------------------------------------
__global__ __launch_bounds__(256) void proj_out(
    const short* __restrict__ Opart, const float* __restrict__ lpart,
    const float* __restrict__ wo, const float* __restrict__ bo,
    float* __restrict__ out) {
    __shared__ __align__(16) short at2[2][16384]; // 64 KB dbuf
    int t = threadIdx.x;
    int m0 = blockIdx.x * 64;
    int lane = t & 63, wv = t >> 6, quad = lane >> 4, idx = lane & 15;

    // wo B-fragments (bf16) in registers
    bf16x8 bw[8];
#pragma unroll
    for (int c = 0; c < 8; c++) {
        const float* ws = wo + idx * E_ + c * 32 + quad * 8;
        f32x4 w0 = *(const f32x4*)ws;
        f32x4 w1 = *(const f32x4*)(ws + 4);
        bw[c] = pack8(w0, w1);
    }

    // stage slice 0
#pragma unroll
    for (int j = 0; j < 8; j++)
        gl_lds16(Opart + (size_t)m0 * E_ + (wv * 8 + j) * 512 + lane * 8,
                 &at2[0][(wv * 8 + j) * 512]);

    f32x4 acc = {0.f, 0.f, 0.f, 0.f};
    for (int ns = 0; ns < NS_; ns++) {
        __syncthreads();
        if (ns + 1 < NS_) {
            const short* src = Opart + ((size_t)(ns + 1) * BS_ + m0) * E_ + lane * 8;
#pragma unroll
            for (int j = 0; j < 8; j++)
                gl_lds16(src + (wv * 8 + j) * 512, &at2[(ns + 1) & 1][(wv * 8 + j) * 512]);
        }
        const short* a = at2[ns & 1];
#pragma unroll
        for (int c = 0; c < 8; c++) {
            bf16x8 af = *(const bf16x8*)&a[(wv * 16 + idx) * 256 +
                                           ((((c * 4 + quad) ^ (idx & 7)) << 3))];
            acc = __builtin_amdgcn_mfma_f32_16x16x32_bf16(af, bw[c], acc, 0, 0, 0);
        }
    }
#pragma unroll
    for (int r = 0; r < 4; r++) {
        int m = m0 + wv * 16 + quad * 4 + r;
        float ltot = 0.f;
#pragma unroll
        for (int ns = 0; ns < NS_; ns++) ltot += lpart[(size_t)ns * BS_ + m];
        out[(size_t)m * NC_ + idx] = acc[r] * (0.0625f / ltot) + bo[idx];
    }
}

extern "C" void kernel_launch(void* const* d_in, const int* in_sizes, int n_in,
                              void* d_out, int out_size, void* d_ws, size_t ws_size,
                              hipStream_t stream) {
    const float* x  = (const float*)d_in[0];
    const float* wq = (const float*)d_in[1];
    const float* bq = (const float*)d_in[2];
    const float* wk = (const float*)d_in[3];
    const float* bk = (const float*)d_in[4];
    const float* wv = (const float*)d_in[5];
    const float* bv = (const float*)d_in[6];
    const float* wo = (const float*)d_in[7];
    const float* bo = (const float*)d_in[8];
    float* out = (float*)d_out;

    const size_t NEL = (size_t)BS_ * E_; // 4,194,304
    // ws: Qb 8MB | Kb 8MB | Vtc 8MB | Opart 32MB | lpart 256KB = 56.25 MB
    short* Qb = (short*)d_ws;
    short* Kb = Qb + NEL;
    short* Vtc = Kb + NEL;
    short* Opart = Vtc + NEL;
    float* lpart = (float*)(Opart + (size_t)NS_ * NEL);

    qkv_gemm<<<dim3(3, BS_ / 64), 256, 0, stream>>>(x, wq, wk, wv, bq, bk, bv, Qb, Kb, Vtc);
    flash_attn<<<dim3(S_ / 256, NS_, B_), 256, 0, stream>>>(Qb, Kb, Vtc, Opart, lpart);
    proj_out<<<BS_ / 64, 256, 0, stream>>>(Opart, lpart, wo, bo, out);
}

// Round 7
// 179.922 us; speedup vs baseline: 1.2751x; 1.2751x over previous
//
#include <hip/hip_runtime.h>
#include <hip/hip_bf16.h>

// B=4, S=4096, E=256, NC=16, fp32 in/out. 3 launches:
//  qkv_gemm: direct fp32 loads + VALU pack staging, MFMA, LDS-routed epilogues
//            (Q *1/16, K block-swizzled rows, V chunk slabs with key-interleave
//             permutation matching flash's packed-P column order)
//  flash:    Q-tile 128 (u=2), 2 blocks/CU, K dbuf + V dbuf + ps sbuf (72 KB),
//            ONE barrier/chunk, one-behind PV so exp hides under PV MFMAs,
//            DMAs get a full chunk of flight before their draining barrier.
//  proj:     MFMA output projection + slice merge + normalize (dbuf staging)

#define S_ 4096
#define E_ 256
#define B_ 4
#define NC_ 16
#define BS_ (B_ * S_)
#define NS_ 4

typedef __attribute__((ext_vector_type(8))) short bf16x8;
typedef __attribute__((ext_vector_type(4))) float f32x4;

__device__ __forceinline__ unsigned short bf16_rtne(float f) {
    unsigned int u = __float_as_uint(f);
    return (unsigned short)((u + 0x7FFFu + ((u >> 16) & 1u)) >> 16);
}
__device__ __forceinline__ bf16x8 pack8(f32x4 a, f32x4 b) {
    bf16x8 r;
#pragma unroll
    for (int i = 0; i < 4; i++) r[i] = (short)bf16_rtne(a[i]);
#pragma unroll
    for (int i = 0; i < 4; i++) r[4 + i] = (short)bf16_rtne(b[i]);
    return r;
}
__device__ __forceinline__ void gl_lds16(const void* g, void* lds) {
    __builtin_amdgcn_global_load_lds(
        (const __attribute__((address_space(1))) unsigned int*)g,
        (__attribute__((address_space(3))) unsigned int*)lds, 16, 0, 0);
}

// ---------------------------------------------------------------------------
// qkv_gemm. Grid (3 sel, BS_/64). 256 thr = 4 waves; wave: 16 rows x 256 cols.
// ---------------------------------------------------------------------------
__global__ __launch_bounds__(256) void qkv_gemm(
    const float* __restrict__ x, const float* __restrict__ wq,
    const float* __restrict__ wk, const float* __restrict__ wv,
    const float* __restrict__ bq, const float* __restrict__ bk,
    const float* __restrict__ bv, short* __restrict__ Qb,
    short* __restrict__ Kb, short* __restrict__ Vtc) {
    __shared__ bf16x8 xt[256];   // 4 KB
    __shared__ bf16x8 wt[1024];  // 16 KB
    __shared__ short epi[16896]; // 64x264 (Q/K) or 2x8192 slabs (V)

    int t = threadIdx.x;
    int sel = blockIdx.x, m0 = blockIdx.y * 64;
    int lane = t & 63, wid = t >> 6, quad = lane >> 4, idx = lane & 15;

    const float* w = (sel == 0) ? wq : (sel == 1) ? wk : wv;
    const float* bias = (sel == 0) ? bq : (sel == 1) ? bk : bv;

    const float* xsrc = x + (size_t)(m0 + (t >> 2)) * E_ + (t & 3) * 8;

    f32x4 zf = {0.f, 0.f, 0.f, 0.f};
    f32x4 acc[16];
#pragma unroll
    for (int i = 0; i < 16; i++) acc[i] = zf;

    for (int kc = 0; kc < E_; kc += 32) {
        f32x4 a0 = *(const f32x4*)(xsrc + kc);
        f32x4 a1 = *(const f32x4*)(xsrc + kc + 4);
        xt[t] = pack8(a0, a1);
#pragma unroll
        for (int i = 0; i < 4; i++) {
            int p = i * 256 + t;
            const float* ws = w + (size_t)(p >> 2) * E_ + (p & 3) * 8 + kc;
            f32x4 b0 = *(const f32x4*)ws;
            f32x4 b1 = *(const f32x4*)(ws + 4);
            wt[p] = pack8(b0, b1);
        }
        __syncthreads();
        bf16x8 af = xt[(wid * 16 + idx) * 4 + quad];
#pragma unroll
        for (int ct = 0; ct < 16; ct++)
            acc[ct] = __builtin_amdgcn_mfma_f32_16x16x32_bf16(
                af, wt[(ct * 16 + idx) * 4 + quad], acc[ct], 0, 0, 0);
        __syncthreads();
    }

    int qr = quad * 4;
    if (sel == 2) {
        // V: chunk slab, position = key-interleave permutation + 16B swizzle
#pragma unroll
        for (int ct = 0; ct < 16; ct++) {
            int e = ct * 16 + idx;
            float bb = bias[e];
#pragma unroll
            for (int r = 0; r < 4; r++) {
                int mr = wid * 16 + qr + r; // 0..63
                int ckg = mr >> 5, sin = mr & 31;
                int sp = ((sin & 15) << 1) | (sin >> 4); // interleaved position
                int pos = (sp >> 3) ^ ((e >> 1) & 3);
                epi[ckg * 8192 + e * 32 + pos * 8 + (sp & 7)] =
                    (short)bf16_rtne(acc[ct][r] + bb);
            }
        }
        __syncthreads();
        size_t base = ((size_t)((m0 >> 12) * 128 + ((m0 & (S_ - 1)) >> 5))) * 8192;
#pragma unroll
        for (int j = 0; j < 8; j++) {
            int unit = j * 256 + t;
            *(bf16x8*)(Vtc + base + (size_t)unit * 8) = *(const bf16x8*)&epi[unit * 8];
        }
    } else {
        float alpha = (sel == 0) ? 0.0625f : 1.0f;
#pragma unroll
        for (int ct = 0; ct < 16; ct++) {
            int n = ct * 16 + idx;
            float bb = bias[n];
#pragma unroll
            for (int r = 0; r < 4; r++) {
                int row = wid * 16 + qr + r;
                int col = (sel == 1) ? ((((n >> 3) ^ (row & 7)) << 3) | (n & 7)) : n;
                epi[row * 264 + col] = (short)bf16_rtne((acc[ct][r] + bb) * alpha);
            }
        }
        __syncthreads();
        short* out = (sel == 0) ? Qb : Kb;
#pragma unroll
        for (int j = 0; j < 8; j++) {
            int g = j * 256 + t;
            int row = g >> 5, seg = g & 31;
            *(bf16x8*)(out + (size_t)(m0 + row) * E_ + seg * 8) =
                *(const bf16x8*)&epi[row * 264 + seg * 8];
        }
    }
}

// ---------------------------------------------------------------------------
// Flash. Grid (S/128, NS, B). 256 thr = 4 waves; wave owns 2 q-subtiles of 16.
// LDS 72 KB: K dbuf 2x16K | V dbuf 2x16K | ps 8K. One barrier per chunk;
// one-behind PV; staging DMAs get a full chunk of flight. P staged packed-b32
// with interleaved key columns; V slabs permuted to match.
// ---------------------------------------------------------------------------
__global__ __launch_bounds__(256, 2) void flash_attn(
    const short* __restrict__ Qb, const short* __restrict__ Kb,
    const short* __restrict__ Vtc, short* __restrict__ Opart,
    float* __restrict__ lpart) {
    __shared__ __align__(16) short lds[36864]; // 72 KB
    // kb(par) = lds + par*8192 ; vb(par) = lds + 16384 + par*8192 ; ps at 32768

    int t = threadIdx.x;
    int b = blockIdx.z, slice = blockIdx.y, q0 = blockIdx.x * 128;
    int key0 = slice * (S_ / NS_);
    const int nchunk = (S_ / NS_) / 32; // 32
    int lane = t & 63, wv = t >> 6, quad = lane >> 4, idx = lane & 15;

    bf16x8 qf[2][8];
#pragma unroll
    for (int u = 0; u < 2; u++) {
        const short* qrow = Qb + (size_t)(b * S_ + q0 + u * 64 + wv * 16 + idx) * E_ + quad * 8;
#pragma unroll
        for (int c = 0; c < 8; c++) qf[u][c] = *(const bf16x8*)(qrow + c * 32);
    }

    f32x4 zf = {0.f, 0.f, 0.f, 0.f};
    f32x4 oacc[2][16];
#pragma unroll
    for (int u = 0; u < 2; u++)
#pragma unroll
        for (int i = 0; i < 16; i++) oacc[u][i] = zf;
    float ls[2][4] = {{0, 0, 0, 0}, {0, 0, 0, 0}};

    const short* kg = Kb + (size_t)(b * S_ + key0) * E_ + lane * 8;
    const short* vg = Vtc + ((size_t)(b * 128 + (key0 >> 5))) * 8192 + lane * 8;
    short* psw = lds + 32768 + wv * 1024;
    unsigned int* pswu = (unsigned int*)psw;
    int vsw = (quad ^ ((idx >> 1) & 3)) << 3;

    // prologue: stage K(0), V(0), K(1)
#pragma unroll
    for (int j = 0; j < 4; j++) gl_lds16(kg + (wv * 4 + j) * 512, &lds[(wv * 4 + j) * 512]);
#pragma unroll
    for (int j = 0; j < 4; j++) gl_lds16(vg + (wv * 4 + j) * 512, &lds[16384 + (wv * 4 + j) * 512]);
#pragma unroll
    for (int j = 0; j < 4; j++) gl_lds16(kg + 8192 + (wv * 4 + j) * 512, &lds[8192 + (wv * 4 + j) * 512]);
    __syncthreads();

    // QK(0) + exp(0)
    {
        f32x4 s[4] = {zf, zf, zf, zf};
#pragma unroll
        for (int c = 0; c < 8; c++) {
            int p = (((c * 4 + quad) ^ (idx & 7)) << 3);
            bf16x8 k0 = *(const bf16x8*)&lds[idx * 256 + p];
            bf16x8 k1 = *(const bf16x8*)&lds[(16 + idx) * 256 + p];
            s[0] = __builtin_amdgcn_mfma_f32_16x16x32_bf16(qf[0][c], k0, s[0], 0, 0, 0);
            s[1] = __builtin_amdgcn_mfma_f32_16x16x32_bf16(qf[0][c], k1, s[1], 0, 0, 0);
            s[2] = __builtin_amdgcn_mfma_f32_16x16x32_bf16(qf[1][c], k0, s[2], 0, 0, 0);
            s[3] = __builtin_amdgcn_mfma_f32_16x16x32_bf16(qf[1][c], k1, s[3], 0, 0, 0);
        }
#pragma unroll
        for (int u = 0; u < 2; u++)
#pragma unroll
            for (int r = 0; r < 4; r++) {
                float p0 = __expf(s[u * 2][r]);
                float p1 = __expf(s[u * 2 + 1][r]);
                ls[u][r] += p0 + p1;
                pswu[u * 256 + (quad * 4 + r) * 16 + idx] =
                    (unsigned int)bf16_rtne(p0) | ((unsigned int)bf16_rtne(p1) << 16);
            }
    }

    for (int ck = 0; ck < nchunk - 1; ck++) {
        __syncthreads(); // drains K(ck+1), V(ck) DMAs (staged one full chunk ago)
        if (ck + 2 < nchunk) {
            const short* ks = kg + (size_t)(ck + 2) * 8192;
            short* kd = lds + (ck & 1) * 8192;
#pragma unroll
            for (int j = 0; j < 4; j++) gl_lds16(ks + (wv * 4 + j) * 512, &kd[(wv * 4 + j) * 512]);
        }
        {
            const short* vs = vg + (size_t)(ck + 1) * 8192;
            short* vd = lds + 16384 + ((ck + 1) & 1) * 8192;
#pragma unroll
            for (int j = 0; j < 4; j++) gl_lds16(vs + (wv * 4 + j) * 512, &vd[(wv * 4 + j) * 512]);
        }
        // ---- QK(ck+1) ----
        const short* kc = lds + ((ck + 1) & 1) * 8192;
        f32x4 s[4] = {zf, zf, zf, zf};
#pragma unroll
        for (int c = 0; c < 8; c++) {
            int p = (((c * 4 + quad) ^ (idx & 7)) << 3);
            bf16x8 k0 = *(const bf16x8*)&kc[idx * 256 + p];
            bf16x8 k1 = *(const bf16x8*)&kc[(16 + idx) * 256 + p];
            s[0] = __builtin_amdgcn_mfma_f32_16x16x32_bf16(qf[0][c], k0, s[0], 0, 0, 0);
            s[1] = __builtin_amdgcn_mfma_f32_16x16x32_bf16(qf[0][c], k1, s[1], 0, 0, 0);
            s[2] = __builtin_amdgcn_mfma_f32_16x16x32_bf16(qf[1][c], k0, s[2], 0, 0, 0);
            s[3] = __builtin_amdgcn_mfma_f32_16x16x32_bf16(qf[1][c], k1, s[3], 0, 0, 0);
        }
        // ---- af(ck) read (before exp overwrites ps; per-wave DS is in-order)
        bf16x8 af0 = *(const bf16x8*)&psw[idx * 32 + quad * 8];
        bf16x8 af1 = *(const bf16x8*)&psw[512 + idx * 32 + quad * 8];
        // ---- exp(ck+1) -> ps (independent of PV(ck); hides under it) ----
#pragma unroll
        for (int u = 0; u < 2; u++)
#pragma unroll
            for (int r = 0; r < 4; r++) {
                float p0 = __expf(s[u * 2][r]);
                float p1 = __expf(s[u * 2 + 1][r]);
                ls[u][r] += p0 + p1;
                pswu[u * 256 + (quad * 4 + r) * 16 + idx] =
                    (unsigned int)bf16_rtne(p0) | ((unsigned int)bf16_rtne(p1) << 16);
            }
        // ---- PV(ck) ----
        const short* vc = lds + 16384 + (ck & 1) * 8192;
#pragma unroll
        for (int ct = 0; ct < 16; ct++) {
            bf16x8 v = *(const bf16x8*)&vc[(ct * 16 + idx) * 32 + vsw];
            oacc[0][ct] = __builtin_amdgcn_mfma_f32_16x16x32_bf16(af0, v, oacc[0][ct], 0, 0, 0);
            oacc[1][ct] = __builtin_amdgcn_mfma_f32_16x16x32_bf16(af1, v, oacc[1][ct], 0, 0, 0);
        }
    }
    __syncthreads(); // drain V(nchunk-1)
    {
        bf16x8 af0 = *(const bf16x8*)&psw[idx * 32 + quad * 8];
        bf16x8 af1 = *(const bf16x8*)&psw[512 + idx * 32 + quad * 8];
        const short* vc = lds + 16384 + ((nchunk - 1) & 1) * 8192;
#pragma unroll
        for (int ct = 0; ct < 16; ct++) {
            bf16x8 v = *(const bf16x8*)&vc[(ct * 16 + idx) * 32 + vsw];
            oacc[0][ct] = __builtin_amdgcn_mfma_f32_16x16x32_bf16(af0, v, oacc[0][ct], 0, 0, 0);
            oacc[1][ct] = __builtin_amdgcn_mfma_f32_16x16x32_bf16(af1, v, oacc[1][ct], 0, 0, 0);
        }
    }
    __syncthreads(); // all compute reads of kb/vb done; reuse as epilogue scratch

    // ---- row sums ----
#pragma unroll
    for (int u = 0; u < 2; u++)
#pragma unroll
        for (int r = 0; r < 4; r++) {
            float v = ls[u][r];
            v += __shfl_xor(v, 1);
            v += __shfl_xor(v, 2);
            v += __shfl_xor(v, 4);
            v += __shfl_xor(v, 8);
            if (idx == 0)
                lpart[(size_t)slice * BS_ + b * S_ + q0 + u * 64 + wv * 16 + quad * 4 + r] = v;
        }

    // ---- Opart epilogue: per-wave 16 KB scratch (overlays kb/vb) ----
    short* scr = lds + wv * 8192;
#pragma unroll
    for (int u = 0; u < 2; u++)
#pragma unroll
        for (int ct = 0; ct < 16; ct++) {
            int e = ct * 16 + idx;
#pragma unroll
            for (int r = 0; r < 4; r++) {
                int lr = quad * 4 + r;
                scr[u * 4096 + lr * 256 + ((((e >> 3) ^ (lr & 7)) << 3) | (e & 7))] =
                    (short)bf16_rtne(oacc[u][ct][r]);
            }
        }
#pragma unroll
    for (int u = 0; u < 2; u++) {
        size_t obase = ((size_t)slice * BS_ + (size_t)b * S_ + q0 + u * 64 + wv * 16) * E_;
#pragma unroll
        for (int j = 0; j < 8; j++) {
            int unit = j * 64 + lane; // 512 units of 8 shorts
            *(bf16x8*)(Opart + obase + (size_t)unit * 8) =
                *(const bf16x8*)&scr[u * 4096 + unit * 8];
        }
    }
}

// ---------------------------------------------------------------------------
// proj: out[m][o] = (sum_ns sum_e Opart[ns][m][e]*wo[o][e]) * (1/16)/ltot + bo
// ---------------------------------------------------------------------------
__global__ __launch_bounds__(256) void proj_out(
    const short* __restrict__ Opart, const float* __restrict__ lpart,
    const float* __restrict__ wo, const float* __restrict__ bo,
    float* __restrict__ out) {
    __shared__ __align__(16) short at2[2][16384]; // 64 KB dbuf
    int t = threadIdx.x;
    int m0 = blockIdx.x * 64;
    int lane = t & 63, wv = t >> 6, quad = lane >> 4, idx = lane & 15;

    bf16x8 bw[8];
#pragma unroll
    for (int c = 0; c < 8; c++) {
        const float* ws = wo + idx * E_ + c * 32 + quad * 8;
        f32x4 w0 = *(const f32x4*)ws;
        f32x4 w1 = *(const f32x4*)(ws + 4);
        bw[c] = pack8(w0, w1);
    }

#pragma unroll
    for (int j = 0; j < 8; j++)
        gl_lds16(Opart + (size_t)m0 * E_ + (wv * 8 + j) * 512 + lane * 8,
                 &at2[0][(wv * 8 + j) * 512]);

    f32x4 acc = {0.f, 0.f, 0.f, 0.f};
    for (int ns = 0; ns < NS_; ns++) {
        __syncthreads();
        if (ns + 1 < NS_) {
            const short* src = Opart + ((size_t)(ns + 1) * BS_ + m0) * E_ + lane * 8;
#pragma unroll
            for (int j = 0; j < 8; j++)
                gl_lds16(src + (wv * 8 + j) * 512, &at2[(ns + 1) & 1][(wv * 8 + j) * 512]);
        }
        const short* a = at2[ns & 1];
#pragma unroll
        for (int c = 0; c < 8; c++) {
            bf16x8 af = *(const bf16x8*)&a[(wv * 16 + idx) * 256 +
                                           ((((c * 4 + quad) ^ (idx & 7)) << 3))];
            acc = __builtin_amdgcn_mfma_f32_16x16x32_bf16(af, bw[c], acc, 0, 0, 0);
        }
    }
#pragma unroll
    for (int r = 0; r < 4; r++) {
        int m = m0 + wv * 16 + quad * 4 + r;
        float ltot = 0.f;
#pragma unroll
        for (int ns = 0; ns < NS_; ns++) ltot += lpart[(size_t)ns * BS_ + m];
        out[(size_t)m * NC_ + idx] = acc[r] * (0.0625f / ltot) + bo[idx];
    }
}

extern "C" void kernel_launch(void* const* d_in, const int* in_sizes, int n_in,
                              void* d_out, int out_size, void* d_ws, size_t ws_size,
                              hipStream_t stream) {
    const float* x  = (const float*)d_in[0];
    const float* wq = (const float*)d_in[1];
    const float* bq = (const float*)d_in[2];
    const float* wk = (const float*)d_in[3];
    const float* bk = (const float*)d_in[4];
    const float* wv = (const float*)d_in[5];
    const float* bv = (const float*)d_in[6];
    const float* wo = (const float*)d_in[7];
    const float* bo = (const float*)d_in[8];
    float* out = (float*)d_out;

    const size_t NEL = (size_t)BS_ * E_; // 4,194,304
    // ws: Qb 8MB | Kb 8MB | Vtc 8MB | Opart 32MB | lpart 256KB = 56.25 MB
    short* Qb = (short*)d_ws;
    short* Kb = Qb + NEL;
    short* Vtc = Kb + NEL;
    short* Opart = Vtc + NEL;
    float* lpart = (float*)(Opart + (size_t)NS_ * NEL);

    qkv_gemm<<<dim3(3, BS_ / 64), 256, 0, stream>>>(x, wq, wk, wv, bq, bk, bv, Qb, Kb, Vtc);
    flash_attn<<<dim3(S_ / 128, NS_, B_), 256, 0, stream>>>(Qb, Kb, Vtc, Opart, lpart);
    proj_out<<<BS_ / 64, 256, 0, stream>>>(Opart, lpart, wo, bo, out);
}